// Round 7
// baseline (231.198 us; speedup 1.0000x reference)
//
#include <hip/hip_runtime.h>
#include <stdint.h>

// Problem constants (fixed by setup_inputs: B=4, N_obj=8, N_v=2048)
#define NPTS 2048
#define KNN  16
#define AK   64
#define TPB  256
#define FPT  8     // knn staging: points per thread (256-thread block)
#define FPP  4     // fps: v2f pairs per thread (8 points)
#define OPB  4     // fps: objects interleaved per block
#define KPL  32    // knn: points per lane (one wave per anchor)
#define KPP  16    // knn: v2f pairs per lane

typedef unsigned long long u64;
typedef unsigned int u32;
typedef __attribute__((ext_vector_type(2))) float v2f;
#define UMAX 0xFFFFFFFFFFFFFFFFull

// Exact float32 helper (no FMA contraction -> match numpy reference bitwise)
__device__ __forceinline__ float sq3(float x, float y, float z) {
    return __fadd_rn(__fadd_rn(__fmul_rn(x, x), __fmul_rn(y, y)), __fmul_rn(z, z));
}

// ---------------------------------------------------------------------------
// DPP primitives (validated R4/R5/R6, absmax 0.0). Canonical 64-lane
// reduction: quad_perm xor1/xor2, row_half_mirror, row_mirror, row_bcast15
// (row_mask 0xA), row_bcast31 (row_mask 0xC); result in lane 63, readlane ->
// uniform. bound_ctrl=false + old=src => masked lanes self-combine.
// ---------------------------------------------------------------------------
template <int CTRL, int RMASK>
__device__ __forceinline__ u32 dpp32(u32 v) {
    return (u32)__builtin_amdgcn_update_dpp((int)v, (int)v, CTRL, RMASK, 0xF, false);
}

#define FMAX_STEP(CTRL, RMASK) \
    m = fmaxf(m, __uint_as_float(dpp32<CTRL, RMASK>(__float_as_uint(m))))
#define UMIN_STEP(CTRL, RMASK) \
    { const u32 o_ = dpp32<CTRL, RMASK>(c); c = (o_ < c) ? o_ : c; }

__device__ __forceinline__ float wave_fmax(float m) {
    FMAX_STEP(0xB1, 0xF);
    FMAX_STEP(0x4E, 0xF);
    FMAX_STEP(0x141, 0xF);
    FMAX_STEP(0x140, 0xF);
    FMAX_STEP(0x142, 0xA);
    FMAX_STEP(0x143, 0xC);
    return __uint_as_float((u32)__builtin_amdgcn_readlane(
        (int)__float_as_uint(m), 63));
}

__device__ __forceinline__ u32 wave_umin(u32 c) {
    UMIN_STEP(0xB1, 0xF);
    UMIN_STEP(0x4E, 0xF);
    UMIN_STEP(0x141, 0xF);
    UMIN_STEP(0x140, 0xF);
    UMIN_STEP(0x142, 0xA);
    UMIN_STEP(0x143, 0xC);
    return (u32)__builtin_amdgcn_readlane((int)c, 63);
}

// u64 min-combine step (knn key reduction) — identical to validated R4/R5
template <int CTRL, int RMASK>
__device__ __forceinline__ u64 minstep(u64 k) {
    const u32 olo = dpp32<CTRL, RMASK>((u32)k);
    const u32 ohi = dpp32<CTRL, RMASK>((u32)(k >> 32));
    const u64 o = ((u64)ohi << 32) | olo;
    return (o < k) ? o : k;
}

__device__ __forceinline__ u64 wave_min64(u64 k) {
    k = minstep<0xB1, 0xF>(k);
    k = minstep<0x4E, 0xF>(k);
    k = minstep<0x141, 0xF>(k);
    k = minstep<0x140, 0xF>(k);
    k = minstep<0x142, 0xA>(k);
    k = minstep<0x143, 0xC>(k);
    const u32 lo = (u32)__builtin_amdgcn_readlane((int)(u32)k, 63);
    const u32 hi = (u32)__builtin_amdgcn_readlane((int)(u32)(k >> 32), 63);
    return ((u64)hi << 32) | lo;
}

// ---------------------------------------------------------------------------
// Kernel 1: farthest-point sampling, FOUR objects interleaved per block
// (4 waves, R5's validated per-object step). Between two barriers the block
// carries 4 independent scan+reduce+merge dataflows -> chain latency of each
// hides behind the issue of the others; ONE __syncthreads per step serves
// all four exchanges. Per-object semantics byte-identical to R5.
// ---------------------------------------------------------------------------
__global__ __launch_bounds__(TPB, 1) void fps_kernel(const float* __restrict__ pos,
                                                     int* __restrict__ anchors) {
#pragma clang fp contract(off)
    const int ob = blockIdx.x * OPB;     // first object of this block
    const int t = threadIdx.x;
    const int wid = t >> 6;

    __shared__ u64 skey[OPB][8];     // [obj][side*4 + wave] double-buffered
    __shared__ float4 scrd[OPB][8];

    v2f px[OPB][FPP], py[OPB][FPP], pz[OPB][FPP], mind[OPB][FPP];
    float bv[OPB], bx[OPB], by[OPB], bz[OPB];
    u32 bj[OPB];

    #pragma unroll
    for (int o = 0; o < OPB; o++) {
        const float* pts = pos + (size_t)(ob + o) * NPTS * 3;
        const float ax0 = pts[0], ay0 = pts[1], az0 = pts[2];
        bv[o] = -1.0f; bj[o] = 0; bx[o] = by[o] = bz[o] = 0.0f;
        #pragma unroll
        for (int i = 0; i < FPP; i++) {
            const int jA = t + (2 * i) * TPB;      // jA < jB, i ascending ->
            const int jB = t + (2 * i + 1) * TPB;  // ascending j per thread
            v2f X, Y, Z;
            X.x = pts[jA * 3 + 0]; Y.x = pts[jA * 3 + 1]; Z.x = pts[jA * 3 + 2];
            X.y = pts[jB * 3 + 0]; Y.y = pts[jB * 3 + 1]; Z.y = pts[jB * 3 + 2];
            px[o][i] = X; py[o][i] = Y; pz[o][i] = Z;
            const v2f dx = X - ax0, dy = Y - ay0, dz = Z - az0;
            const v2f d2 = dx * dx + dy * dy + dz * dz;  // ((x2+y2)+z2), no fma
            mind[o][i] = d2;
            if (d2.x > bv[o]) { bv[o] = d2.x; bj[o] = (u32)jA;
                                bx[o] = X.x; by[o] = Y.x; bz[o] = Z.x; }
            if (d2.y > bv[o]) { bv[o] = d2.y; bj[o] = (u32)jB;
                                bx[o] = X.y; by[o] = Y.y; bz[o] = Z.y; }
        }
        if (t == 0) anchors[(ob + o) * AK + 0] = 0;
    }

    for (int s = 1; s < AK; s++) {
        const int side = (s & 1) * 4;

        // Phase 1+2 per object (independent chains -> compiler interleaves):
        // wave max of value, then min j among lanes achieving it. Exactly the
        // u64-key winner (max value, smallest j) — validated R5.
        #pragma unroll
        for (int o = 0; o < OPB; o++) {
            const float wmax = wave_fmax(bv[o]);
            const u32 cand = (bv[o] == wmax) ? bj[o] : 0xFFFFFFFFu;
            const u32 wj = wave_umin(cand);
            if (bv[o] == wmax && bj[o] == wj) {  // exactly one lane per wave
                skey[o][side + wid] = ((u64)__float_as_uint(wmax) << 32)
                                      | (u32)(~wj);
                scrd[o][side + wid] = make_float4(bx[o], by[o], bz[o], 0.0f);
            }
        }
        __syncthreads();   // ONE barrier per step for all 4 objects

        // 4-way merge + anchor write + fused min-update/argmax scan, per obj.
        #pragma unroll
        for (int o = 0; o < OPB; o++) {
            u64 ka = skey[o][side + 0];
            float4 ca = scrd[o][side + 0];
            { const u64 kb = skey[o][side + 1]; const float4 cb = scrd[o][side + 1];
              if (kb > ka) { ka = kb; ca = cb; } }
            { const u64 kb = skey[o][side + 2]; const float4 cb = scrd[o][side + 2];
              if (kb > ka) { ka = kb; ca = cb; } }
            { const u64 kb = skey[o][side + 3]; const float4 cb = scrd[o][side + 3];
              if (kb > ka) { ka = kb; ca = cb; } }
            if (t == 0) anchors[(ob + o) * AK + s] = (int)(~(u32)ka);
            if (s == AK - 1) continue;   // no update after last anchor

            bv[o] = -1.0f; bj[o] = 0;
            #pragma unroll
            for (int i = 0; i < FPP; i++) {
                const v2f dx = px[o][i] - ca.x, dy = py[o][i] - ca.y,
                          dz = pz[o][i] - ca.z;
                const v2f d2 = dx * dx + dy * dy + dz * dz;
                v2f nm;
                nm.x = fminf(mind[o][i].x, d2.x);
                nm.y = fminf(mind[o][i].y, d2.y);
                mind[o][i] = nm;
                if (nm.x > bv[o]) { bv[o] = nm.x; bj[o] = (u32)(t + (2 * i) * TPB);
                                    bx[o] = px[o][i].x; by[o] = py[o][i].x;
                                    bz[o] = pz[o][i].x; }
                if (nm.y > bv[o]) { bv[o] = nm.y;
                                    bj[o] = (u32)(t + (2 * i + 1) * TPB);
                                    bx[o] = px[o][i].y; by[o] = py[o][i].y;
                                    bz[o] = pz[o][i].y; }
            }
        }
    }
}

// ---------------------------------------------------------------------------
// Kernel 2: KNN dist-vec + gather + concat. ONE WAVE per anchor, 4 anchors
// per block. UNCHANGED from the validated R4/R5/R6 kernel: per-lane sorted
// top-2 cache, rare threshold refill, DPP u64 wave-min.
// ---------------------------------------------------------------------------
__global__ __launch_bounds__(TPB) void knn_gather_kernel(
    const float* __restrict__ pos, const float* __restrict__ vel,
    const float* __restrict__ phys, const float* __restrict__ refp,
    const int* __restrict__ anchors, float* __restrict__ out) {
#pragma clang fp contract(off)
    const int t = threadIdx.x;
    const int wid = t >> 6, lane = t & 63;
    const int g = blockIdx.x * 4 + wid;   // global anchor id (obj*64 + k)
    const int obj = g >> 6;

    __shared__ float sX[NPTS], sY[NPTS], sZ[NPTS];   // SoA, bank-perfect
    const float* pts = pos + (size_t)obj * NPTS * 3;
    #pragma unroll
    for (int i = 0; i < FPT; i++) {
        const int j = t + i * TPB;
        sX[j] = pts[j * 3 + 0];
        sY[j] = pts[j * 3 + 1];
        sZ[j] = pts[j * 3 + 2];
    }
    const int a = anchors[g];   // global read, no LDS hazard
    __syncthreads();            // the only barrier

    const float ax = sX[a], ay = sY[a], az = sZ[a];
    const float sqa = sq3(ax, ay, az);

    // d2 row exactly as reference: (sq_a + sq_j) - 2*dot; packed-fp32 pairs,
    // per-component rounding identical to the scalar __f*_rn sequence.
    u64 k[KPL];
    #pragma unroll
    for (int i = 0; i < KPP; i++) {
        const int jA = lane + (2 * i) * 64, jB = lane + (2 * i + 1) * 64;
        v2f X, Y, Z;
        X.x = sX[jA]; Y.x = sY[jA]; Z.x = sZ[jA];
        X.y = sX[jB]; Y.y = sY[jB]; Z.y = sZ[jB];
        const v2f sqj = X * X + Y * Y + Z * Z;          // ((x2+y2)+z2)
        const v2f dot = ax * X + ay * Y + az * Z;       // ((ax*x+ay*y)+az*z)
        const v2f d2 = (sqa + sqj) - 2.0f * dot;
        u32 b0 = __float_as_uint(d2.x);
        b0 ^= (b0 & 0x80000000u) ? 0xFFFFFFFFu : 0x80000000u;  // sortable
        u32 b1 = __float_as_uint(d2.y);
        b1 ^= (b1 & 0x80000000u) ? 0xFFFFFFFFu : 0x80000000u;
        k[2 * i]     = (jA == a) ? UMAX : (((u64)b0 << 32) | (u32)jA);
        k[2 * i + 1] = (jB == a) ? UMAX : (((u64)b1 << 32) | (u32)jB);
    }

    // per-lane 2 smallest, ascending: c0 < c1 (keys unique)
    u64 c0 = UMAX, c1 = UMAX;
    #pragma unroll
    for (int i = 0; i < KPL; i++) c0 = (k[i] < c0) ? k[i] : c0;
    #pragma unroll
    for (int i = 0; i < KPL; i++) {
        const u64 v = (k[i] > c0) ? k[i] : UMAX; c1 = (v < c1) ? v : c1;
    }

    float accx = 0.f, accy = 0.f, accz = 0.f;
    u64 thr = 0;
    for (int r = 0; r < KNN; r++) {
        if (c0 == UMAX) {   // rare refill: 2 smallest keys > thr
            #pragma unroll
            for (int i = 0; i < KPL; i++) {
                const u64 v = (k[i] > thr) ? k[i] : UMAX; c0 = (v < c0) ? v : c0;
            }
            #pragma unroll
            for (int i = 0; i < KPL; i++) {
                const u64 v = (k[i] > c0) ? k[i] : UMAX; c1 = (v < c1) ? v : c1;
            }
        }
        const u64 w = wave_min64(c0);       // global min; keys unique
        const int winj = (int)(u32)w;
        // accumulate in ascending-distance order (== top_k output order);
        // uniform LDS reads broadcast, off the pop critical path.
        accx = __fadd_rn(accx, __fsub_rn(sX[winj], ax));
        accy = __fadd_rn(accy, __fsub_rn(sY[winj], ay));
        accz = __fadd_rn(accz, __fsub_rn(sZ[winj], az));
        if (c0 == w) {                       // exactly one lane pops
            thr = c0; c0 = c1; c1 = UMAX;
        }
    }

    if (lane == 0) {
        float* o = out + (size_t)g * 12;
        o[0] = __fmul_rn(accx, 0.0625f);   // /16 exact as *2^-4
        o[1] = __fmul_rn(accy, 0.0625f);
        o[2] = __fmul_rn(accz, 0.0625f);
        const size_t base = (size_t)obj * NPTS * 3 + (size_t)a * 3;
        o[3] = vel[base + 0];
        o[4] = vel[base + 1];
        o[5] = vel[base + 2];
        o[6] = __fsub_rn(pos[base + 0], refp[base + 0]);
        o[7] = __fsub_rn(pos[base + 1], refp[base + 1]);
        o[8] = __fsub_rn(pos[base + 2], refp[base + 2]);
        const float* ph = phys + (size_t)obj * 3;
        o[9]  = ph[0];
        o[10] = ph[1];
        o[11] = ph[2];
    }
}

extern "C" void kernel_launch(void* const* d_in, const int* in_sizes, int n_in,
                              void* d_out, int out_size, void* d_ws, size_t ws_size,
                              hipStream_t stream) {
    const float* pos  = (const float*)d_in[0];  // (4,8,2048,3)
    const float* vel  = (const float*)d_in[1];  // (4,8,2048,3)
    const float* phys = (const float*)d_in[2];  // (4,8,3)
    const float* refp = (const float*)d_in[3];  // (4,8,2048,3)
    float* out = (float*)d_out;                 // (4,8,64,12)

    const int n_obj = in_sizes[2] / 3;          // 32 objects
    int* anchors = (int*)d_ws;                  // n_obj * 64 ints

    fps_kernel<<<n_obj / OPB, TPB, 0, stream>>>(pos, anchors);
    knn_gather_kernel<<<n_obj * AK / 4, TPB, 0, stream>>>(pos, vel, phys, refp,
                                                          anchors, out);
}

// Round 8
// 121.882 us; speedup vs baseline: 1.8969x; 1.8969x over previous
//
#include <hip/hip_runtime.h>
#include <stdint.h>

// Problem constants (fixed by setup_inputs: B=4, N_obj=8, N_v=2048)
#define NPTS 2048
#define KNN  16
#define AK   64
#define TPB  256
#define FPT  8     // knn staging: points per thread (256-thread block)
#define KPL  32    // points per lane (one wave covers 2048)
#define KPP  16    // v2f pairs per lane

typedef unsigned long long u64;
typedef unsigned int u32;
typedef __attribute__((ext_vector_type(2))) float v2f;
#define UMAX 0xFFFFFFFFFFFFFFFFull

// Exact float32 helper (no FMA contraction -> match numpy reference bitwise)
__device__ __forceinline__ float sq3(float x, float y, float z) {
    return __fadd_rn(__fadd_rn(__fmul_rn(x, x), __fmul_rn(y, y)), __fmul_rn(z, z));
}

// ---------------------------------------------------------------------------
// DPP primitives (validated R4-R7, absmax 0.0). Canonical 64-lane reduction:
// quad_perm xor1/xor2, row_half_mirror, row_mirror, row_bcast15 (row_mask
// 0xA), row_bcast31 (row_mask 0xC); result in lane 63, readlane -> uniform.
// ---------------------------------------------------------------------------
template <int CTRL, int RMASK>
__device__ __forceinline__ u32 dpp32(u32 v) {
    return (u32)__builtin_amdgcn_update_dpp((int)v, (int)v, CTRL, RMASK, 0xF, false);
}

#define FMAX_STEP(CTRL, RMASK) \
    m = fmaxf(m, __uint_as_float(dpp32<CTRL, RMASK>(__float_as_uint(m))))
#define UMIN_STEP(CTRL, RMASK) \
    { const u32 o_ = dpp32<CTRL, RMASK>(c); c = (o_ < c) ? o_ : c; }

__device__ __forceinline__ float wave_fmax(float m) {
    FMAX_STEP(0xB1, 0xF);
    FMAX_STEP(0x4E, 0xF);
    FMAX_STEP(0x141, 0xF);
    FMAX_STEP(0x140, 0xF);
    FMAX_STEP(0x142, 0xA);
    FMAX_STEP(0x143, 0xC);
    return __uint_as_float((u32)__builtin_amdgcn_readlane(
        (int)__float_as_uint(m), 63));
}

__device__ __forceinline__ u32 wave_umin(u32 c) {
    UMIN_STEP(0xB1, 0xF);
    UMIN_STEP(0x4E, 0xF);
    UMIN_STEP(0x141, 0xF);
    UMIN_STEP(0x140, 0xF);
    UMIN_STEP(0x142, 0xA);
    UMIN_STEP(0x143, 0xC);
    return (u32)__builtin_amdgcn_readlane((int)c, 63);
}

// u64 min-combine step (knn key reduction) — identical to validated R4-R7
template <int CTRL, int RMASK>
__device__ __forceinline__ u64 minstep(u64 k) {
    const u32 olo = dpp32<CTRL, RMASK>((u32)k);
    const u32 ohi = dpp32<CTRL, RMASK>((u32)(k >> 32));
    const u64 o = ((u64)ohi << 32) | olo;
    return (o < k) ? o : k;
}

__device__ __forceinline__ u64 wave_min64(u64 k) {
    k = minstep<0xB1, 0xF>(k);
    k = minstep<0x4E, 0xF>(k);
    k = minstep<0x141, 0xF>(k);
    k = minstep<0x140, 0xF>(k);
    k = minstep<0x142, 0xA>(k);
    k = minstep<0x143, 0xC>(k);
    const u32 lo = (u32)__builtin_amdgcn_readlane((int)(u32)k, 63);
    const u32 hi = (u32)__builtin_amdgcn_readlane((int)(u32)(k >> 32), 63);
    return ((u64)hi << 32) | lo;
}

// ---------------------------------------------------------------------------
// Kernel 1: farthest-point sampling, ONE WAVE per object (64-thread block).
// Points live in registers (32/lane, v2f pairs); the cloud is ALSO staged
// once to LDS (SoA) so winner coords are 3 uniform ds_reads (~130 cyc) —
// replacing R6's catastrophic 32-branch register select. Single-wave block:
// no __syncthreads anywhere; program order + lgkmcnt give LDS visibility.
// Scan + two-phase DPP reduction byte-identical to validated R6.
// ---------------------------------------------------------------------------
__global__ __launch_bounds__(64) void fps_kernel(const float* __restrict__ pos,
                                                 int* __restrict__ anchors) {
#pragma clang fp contract(off)
    const int obj = blockIdx.x;
    const int lane = threadIdx.x;        // one wave: 0..63
    const float* pts = pos + (size_t)obj * NPTS * 3;

    __shared__ float sX[NPTS], sY[NPTS], sZ[NPTS];   // 24 KB SoA cloud

    v2f px[KPP], py[KPP], pz[KPP], mind[KPP];
    float bv = -1.0f;
    u32 bj = 0;
    {
        const float ax0 = pts[0], ay0 = pts[1], az0 = pts[2];
        #pragma unroll
        for (int i = 0; i < KPP; i++) {
            const int jA = lane + (2 * i) * 64;      // jA < jB, i ascending ->
            const int jB = lane + (2 * i + 1) * 64;  // ascending j per lane
            v2f X, Y, Z;
            X.x = pts[jA * 3 + 0]; Y.x = pts[jA * 3 + 1]; Z.x = pts[jA * 3 + 2];
            X.y = pts[jB * 3 + 0]; Y.y = pts[jB * 3 + 1]; Z.y = pts[jB * 3 + 2];
            px[i] = X; py[i] = Y; pz[i] = Z;
            sX[jA] = X.x; sY[jA] = Y.x; sZ[jA] = Z.x;   // one-time LDS stage
            sX[jB] = X.y; sY[jB] = Y.y; sZ[jB] = Z.y;
            const v2f dx = X - ax0, dy = Y - ay0, dz = Z - az0;
            const v2f d2 = dx * dx + dy * dy + dz * dz;  // ((x2+y2)+z2), no fma
            mind[i] = d2;
            if (d2.x > bv) { bv = d2.x; bj = (u32)jA; }  // strict >: smallest j
            if (d2.y > bv) { bv = d2.y; bj = (u32)jB; }
        }
    }
    if (lane == 0) anchors[obj * AK + 0] = 0;

    for (int s = 1; s < AK; s++) {
        // Phase 1: wave max of the value (6 dependent DPP v_max_f32).
        const float wmax = wave_fmax(bv);
        // Phase 2: smallest j among lanes achieving wmax — exact u64-key
        // winner (max value, then min j) == jnp.argmax first occurrence.
        const u32 cand = (bv == wmax) ? bj : 0xFFFFFFFFu;
        const u32 wj = wave_umin(cand);
        if (lane == 0) anchors[obj * AK + s] = (int)wj;   // off critical path
        if (s == AK - 1) break;

        // Winner coords: wj is SGPR-uniform -> 3 broadcast ds_reads.
        const float cx = sX[wj], cy = sY[wj], cz = sZ[wj];

        // fused min-update + argmax scan (exact: direct (p-b)^2 like lax.scan)
        bv = -1.0f; bj = 0;
        #pragma unroll
        for (int i = 0; i < KPP; i++) {
            const v2f dx = px[i] - cx, dy = py[i] - cy, dz = pz[i] - cz;
            const v2f d2 = dx * dx + dy * dy + dz * dz;
            v2f nm;
            nm.x = fminf(mind[i].x, d2.x);
            nm.y = fminf(mind[i].y, d2.y);
            mind[i] = nm;
            if (nm.x > bv) { bv = nm.x; bj = (u32)(lane + (2 * i) * 64); }
            if (nm.y > bv) { bv = nm.y; bj = (u32)(lane + (2 * i + 1) * 64); }
        }
    }
}

// ---------------------------------------------------------------------------
// Kernel 2: KNN dist-vec + gather + concat. ONE WAVE per anchor, 4 anchors
// per block. UNCHANGED from the validated R4-R7 kernel: per-lane sorted
// top-2 cache, rare threshold refill, DPP u64 wave-min.
// ---------------------------------------------------------------------------
__global__ __launch_bounds__(TPB) void knn_gather_kernel(
    const float* __restrict__ pos, const float* __restrict__ vel,
    const float* __restrict__ phys, const float* __restrict__ refp,
    const int* __restrict__ anchors, float* __restrict__ out) {
#pragma clang fp contract(off)
    const int t = threadIdx.x;
    const int wid = t >> 6, lane = t & 63;
    const int g = blockIdx.x * 4 + wid;   // global anchor id (obj*64 + k)
    const int obj = g >> 6;

    __shared__ float sX[NPTS], sY[NPTS], sZ[NPTS];   // SoA, bank-perfect
    const float* pts = pos + (size_t)obj * NPTS * 3;
    #pragma unroll
    for (int i = 0; i < FPT; i++) {
        const int j = t + i * TPB;
        sX[j] = pts[j * 3 + 0];
        sY[j] = pts[j * 3 + 1];
        sZ[j] = pts[j * 3 + 2];
    }
    const int a = anchors[g];   // global read, no LDS hazard
    __syncthreads();            // the only barrier

    const float ax = sX[a], ay = sY[a], az = sZ[a];
    const float sqa = sq3(ax, ay, az);

    // d2 row exactly as reference: (sq_a + sq_j) - 2*dot; packed-fp32 pairs,
    // per-component rounding identical to the scalar __f*_rn sequence.
    u64 k[KPL];
    #pragma unroll
    for (int i = 0; i < KPP; i++) {
        const int jA = lane + (2 * i) * 64, jB = lane + (2 * i + 1) * 64;
        v2f X, Y, Z;
        X.x = sX[jA]; Y.x = sY[jA]; Z.x = sZ[jA];
        X.y = sX[jB]; Y.y = sY[jB]; Z.y = sZ[jB];
        const v2f sqj = X * X + Y * Y + Z * Z;          // ((x2+y2)+z2)
        const v2f dot = ax * X + ay * Y + az * Z;       // ((ax*x+ay*y)+az*z)
        const v2f d2 = (sqa + sqj) - 2.0f * dot;
        u32 b0 = __float_as_uint(d2.x);
        b0 ^= (b0 & 0x80000000u) ? 0xFFFFFFFFu : 0x80000000u;  // sortable
        u32 b1 = __float_as_uint(d2.y);
        b1 ^= (b1 & 0x80000000u) ? 0xFFFFFFFFu : 0x80000000u;
        k[2 * i]     = (jA == a) ? UMAX : (((u64)b0 << 32) | (u32)jA);
        k[2 * i + 1] = (jB == a) ? UMAX : (((u64)b1 << 32) | (u32)jB);
    }

    // per-lane 2 smallest, ascending: c0 < c1 (keys unique)
    u64 c0 = UMAX, c1 = UMAX;
    #pragma unroll
    for (int i = 0; i < KPL; i++) c0 = (k[i] < c0) ? k[i] : c0;
    #pragma unroll
    for (int i = 0; i < KPL; i++) {
        const u64 v = (k[i] > c0) ? k[i] : UMAX; c1 = (v < c1) ? v : c1;
    }

    float accx = 0.f, accy = 0.f, accz = 0.f;
    u64 thr = 0;
    for (int r = 0; r < KNN; r++) {
        if (c0 == UMAX) {   // rare refill: 2 smallest keys > thr
            #pragma unroll
            for (int i = 0; i < KPL; i++) {
                const u64 v = (k[i] > thr) ? k[i] : UMAX; c0 = (v < c0) ? v : c0;
            }
            #pragma unroll
            for (int i = 0; i < KPL; i++) {
                const u64 v = (k[i] > c0) ? k[i] : UMAX; c1 = (v < c1) ? v : c1;
            }
        }
        const u64 w = wave_min64(c0);       // global min; keys unique
        const int winj = (int)(u32)w;
        // accumulate in ascending-distance order (== top_k output order);
        // uniform LDS reads broadcast, off the pop critical path.
        accx = __fadd_rn(accx, __fsub_rn(sX[winj], ax));
        accy = __fadd_rn(accy, __fsub_rn(sY[winj], ay));
        accz = __fadd_rn(accz, __fsub_rn(sZ[winj], az));
        if (c0 == w) {                       // exactly one lane pops
            thr = c0; c0 = c1; c1 = UMAX;
        }
    }

    if (lane == 0) {
        float* o = out + (size_t)g * 12;
        o[0] = __fmul_rn(accx, 0.0625f);   // /16 exact as *2^-4
        o[1] = __fmul_rn(accy, 0.0625f);
        o[2] = __fmul_rn(accz, 0.0625f);
        const size_t base = (size_t)obj * NPTS * 3 + (size_t)a * 3;
        o[3] = vel[base + 0];
        o[4] = vel[base + 1];
        o[5] = vel[base + 2];
        o[6] = __fsub_rn(pos[base + 0], refp[base + 0]);
        o[7] = __fsub_rn(pos[base + 1], refp[base + 1]);
        o[8] = __fsub_rn(pos[base + 2], refp[base + 2]);
        const float* ph = phys + (size_t)obj * 3;
        o[9]  = ph[0];
        o[10] = ph[1];
        o[11] = ph[2];
    }
}

extern "C" void kernel_launch(void* const* d_in, const int* in_sizes, int n_in,
                              void* d_out, int out_size, void* d_ws, size_t ws_size,
                              hipStream_t stream) {
    const float* pos  = (const float*)d_in[0];  // (4,8,2048,3)
    const float* vel  = (const float*)d_in[1];  // (4,8,2048,3)
    const float* phys = (const float*)d_in[2];  // (4,8,3)
    const float* refp = (const float*)d_in[3];  // (4,8,2048,3)
    float* out = (float*)d_out;                 // (4,8,64,12)

    const int n_obj = in_sizes[2] / 3;          // 32 objects
    int* anchors = (int*)d_ws;                  // n_obj * 64 ints

    fps_kernel<<<n_obj, 64, 0, stream>>>(pos, anchors);
    knn_gather_kernel<<<n_obj * AK / 4, TPB, 0, stream>>>(pos, vel, phys, refp,
                                                          anchors, out);
}